// Round 1
// baseline (858.416 us; speedup 1.0000x reference)
//
#include <hip/hip_runtime.h>
#include <hip/hip_bf16.h>
#include <stdint.h>

typedef __attribute__((ext_vector_type(8))) short short8;
typedef __attribute__((ext_vector_type(4))) float floatx4;

__device__ __forceinline__ float bf2f(unsigned short u) {
    union { unsigned int ui; float f; } v; v.ui = ((unsigned int)u) << 16; return v.f;
}
__device__ __forceinline__ unsigned short f2bf(float f) {
    union { float f; unsigned int u; } v; v.f = f;
    unsigned int u = v.u;
    unsigned int r = (u + 0x7fffu + ((u >> 16) & 1u)) >> 16;
    return (unsigned short)r;
}

// ---------------- convert features fp32 -> bf16 ----------------
__global__ __launch_bounds__(256)
void convert_bf16(const float* __restrict__ in, unsigned short* __restrict__ out, int n4) {
    int i = blockIdx.x * blockDim.x + threadIdx.x;
    int stride = gridDim.x * blockDim.x;
    for (; i < n4; i += stride) {
        float4 v = ((const float4*)in)[i];
        ushort4 o;
        o.x = f2bf(v.x); o.y = f2bf(v.y); o.z = f2bf(v.z); o.w = f2bf(v.w);
        ((ushort4*)out)[i] = o;
    }
}

// ---------------- encode: enc[k][i] = valid ? idx : -1, padded to nvoxp ----------------
__global__ __launch_bounds__(256)
void encode_kernel(const int* __restrict__ nbr, const float* __restrict__ valid,
                   int* __restrict__ enc, int nvox, int nvoxp) {
    int k = blockIdx.y;
    int r = blockIdx.x * 256 + threadIdx.x;
    int v = -1;
    if (r < nvox) {
        float f = valid[(size_t)k * nvox + r];
        int ix = nbr[(size_t)k * nvox + r];
        v = (f != 0.f) ? ix : -1;
    }
    enc[(size_t)k * nvoxp + r] = v;
}

// ---------------- pack weights into B-fragment order ----------------
// Wp[kk][ks(2)][nt(4)][lane(64)][j(8)] = W[kk][cin = ks*32 + (lane>>4)*8 + j][cout = nt*16 + (lane&15)]
__global__ __launch_bounds__(256)
void pack_w(const float* __restrict__ W1, const float* __restrict__ W2,
            unsigned short* __restrict__ Wp1, unsigned short* __restrict__ Wp2) {
    int bi = blockIdx.x;               // 0..53
    const float* W = (bi < 27) ? W1 : W2;
    unsigned short* Wp = (bi < 27) ? Wp1 : Wp2;
    int kk = bi % 27;
    int t = threadIdx.x;
    int lane = t & 63, grp = t >> 6;
    int q = lane >> 4, l15 = lane & 15;
    for (int c8 = grp; c8 < 8; c8 += 4) {
        int ks = c8 >> 2, nt = c8 & 3;
        unsigned short* dst = Wp + (((kk*2 + ks)*4 + nt)*64 + lane)*8;
        const float* src = W + kk*4096 + (ks*32 + q*8)*64 + nt*16 + l15;
        #pragma unroll
        for (int j = 0; j < 8; ++j) dst[j] = f2bf(src[j*64]);
    }
}

// ---------------- gathered MFMA conv, software-pipelined ----------------
// block = 256 = 4 waves; wave: 64 voxels (4 subtiles of 16) x 64 out-ch.
// Pipeline: enc slice staged in LDS once; A-fragments double-buffered so the
// next kk's 8 scattered gathers are in flight during the current kk's 32 MFMAs.
__global__ __launch_bounds__(256, 3)
void conv_kernel(const unsigned short* __restrict__ xin, const int* __restrict__ enc,
                 const unsigned short* __restrict__ Wp, const unsigned short* __restrict__ zrow,
                 unsigned short* __restrict__ yout, float* __restrict__ sums,
                 int nvox, int nvoxp) {
    __shared__ int lds_enc[27 * 256];   // 27 KB: this block's neighbor indices, all 27 taps
    __shared__ float sred[128];

    int t = threadIdx.x;
    int wave = t >> 6, lane = t & 63;
    int q = lane >> 4, l15 = lane & 15;
    int m0 = blockIdx.x * 256 + wave * 64;   // < nvoxp always (grid covers pad)

    // ---- stage enc slice: 27 rows x 256 voxels, one coalesced 4B/lane load per row
    {
        size_t base = (size_t)blockIdx.x * 256;
        #pragma unroll
        for (int kk = 0; kk < 27; ++kk)
            lds_enc[kk * 256 + t] = enc[(size_t)kk * nvoxp + base + t];
    }
    if (t < 128) sred[t] = 0.f;
    __syncthreads();

    floatx4 acc[4][4];
    #pragma unroll
    for (int s = 0; s < 4; ++s)
        #pragma unroll
        for (int nt = 0; nt < 4; ++nt) acc[s][nt] = (floatx4){0.f, 0.f, 0.f, 0.f};

    int eb = wave * 64 + l15;   // lane's voxel slot within the block (+ s*16)

#define LOAD_ES(es, kk) { _Pragma("unroll") \
    for (int s_ = 0; s_ < 4; ++s_) es[s_] = lds_enc[(kk) * 256 + eb + s_ * 16]; }

#define GATHER(av, es) { _Pragma("unroll") \
    for (int s_ = 0; s_ < 4; ++s_) { \
        const unsigned short* rp_ = (es[s_] >= 0) ? (xin + (size_t)es[s_] * 64) : zrow; \
        av[0][s_] = *(const short8*)(rp_ + q * 8); \
        av[1][s_] = *(const short8*)(rp_ + 32 + q * 8); \
    } }

#define MFMA_PHASE(av, kk) { \
    __builtin_amdgcn_s_setprio(1); \
    _Pragma("unroll") for (int ks_ = 0; ks_ < 2; ++ks_) { \
        const unsigned short* wb_ = Wp + (((kk) * 2 + ks_) * 4) * 512 + lane * 8; \
        _Pragma("unroll") for (int nt_ = 0; nt_ < 4; ++nt_) { \
            short8 bv_ = *(const short8*)(wb_ + nt_ * 512); \
            _Pragma("unroll") for (int s_ = 0; s_ < 4; ++s_) \
                acc[s_][nt_] = __builtin_amdgcn_mfma_f32_16x16x32_bf16(av[ks_][s_], bv_, acc[s_][nt_], 0, 0, 0); \
        } \
    } \
    __builtin_amdgcn_s_setprio(0); \
}

    short8 avA[2][4], avB[2][4];
    int esE[4], esO[4];

    // prologue: fill avA with kk=0, prime es for kk=1,2
    LOAD_ES(esE, 0);
    LOAD_ES(esO, 1);
    GATHER(avA, esE);
    LOAD_ES(esE, 2);

    #pragma unroll 1
    for (int kkp = 0; kkp < 26; kkp += 2) {
        // phase A: issue gathers for kk=kkp+1, then MFMA kk=kkp on avA
        GATHER(avB, esO);
        int k3 = kkp + 3; if (k3 > 26) k3 = 26;   // clamped dup read, result unused at tail
        LOAD_ES(esO, k3);
        __builtin_amdgcn_sched_barrier(0);
        MFMA_PHASE(avA, kkp);

        // phase B: issue gathers for kk=kkp+2, then MFMA kk=kkp+1 on avB
        GATHER(avA, esE);
        int k4 = kkp + 4; if (k4 > 26) k4 = 26;
        LOAD_ES(esE, k4);
        __builtin_amdgcn_sched_barrier(0);
        MFMA_PHASE(avB, kkp + 1);
    }
    // epilogue: kk=26 (gathered in phase B of kkp=24)
    MFMA_PHASE(avA, 26);

#undef LOAD_ES
#undef GATHER
#undef MFMA_PHASE

    // store: D layout col = lane&15, row = q*4 + reg
    #pragma unroll
    for (int s = 0; s < 4; ++s) {
        int rowb = m0 + s*16 + q*4;
        #pragma unroll
        for (int r = 0; r < 4; ++r) {
            if (rowb + r < nvox) {
                unsigned short* yo = yout + (size_t)(rowb + r)*64 + l15;
                #pragma unroll
                for (int nt = 0; nt < 4; ++nt)
                    yo[nt*16] = f2bf(acc[s][nt][r]);
            }
        }
    }

    // fused per-channel stats (pad rows have acc == 0: every tap hit the zero page)
    #pragma unroll
    for (int nt = 0; nt < 4; ++nt) {
        float s_ = 0.f, q_ = 0.f;
        #pragma unroll
        for (int s = 0; s < 4; ++s)
            #pragma unroll
            for (int r = 0; r < 4; ++r) {
                float v = acc[s][nt][r];
                s_ += v; q_ += v*v;
            }
        atomicAdd(&sred[nt*16 + l15], s_);
        atomicAdd(&sred[64 + nt*16 + l15], q_);
    }
    __syncthreads();
    if (t < 128) atomicAdd(&sums[t], sred[t]);
}

// ---------------- BN scale/bias ----------------
__global__ void finalize_kernel(const float* __restrict__ sums, const float* __restrict__ gamma,
                                const float* __restrict__ beta, float* __restrict__ ab, float invn) {
    int c = threadIdx.x;
    if (c < 64) {
        float mean = sums[c] * invn;
        float var  = sums[64 + c] * invn - mean*mean;
        float a = gamma[c] * rsqrtf(var + 1e-5f);
        ab[c] = a;
        ab[64 + c] = beta[c] - mean * a;
    }
}

// ---------------- BN1 + ReLU in place on y1 (bf16) ----------------
__global__ __launch_bounds__(256)
void bnrelu_kernel(unsigned short* __restrict__ y, const float* __restrict__ ab, int n4) {
    int i = blockIdx.x * blockDim.x + threadIdx.x;
    int stride = gridDim.x * blockDim.x;
    for (; i < n4; i += stride) {
        uint2 v = ((const uint2*)y)[i];
        int c0 = (i*4) & 63;
        float f0 = fmaxf(ab[c0]   * bf2f((unsigned short)(v.x & 0xffffu)) + ab[64 + c0],   0.f);
        float f1 = fmaxf(ab[c0+1] * bf2f((unsigned short)(v.x >> 16))     + ab[64 + c0+1], 0.f);
        float f2 = fmaxf(ab[c0+2] * bf2f((unsigned short)(v.y & 0xffffu)) + ab[64 + c0+2], 0.f);
        float f3 = fmaxf(ab[c0+3] * bf2f((unsigned short)(v.y >> 16))     + ab[64 + c0+3], 0.f);
        uint2 o;
        o.x = (unsigned int)f2bf(f0) | ((unsigned int)f2bf(f1) << 16);
        o.y = (unsigned int)f2bf(f2) | ((unsigned int)f2bf(f3) << 16);
        ((uint2*)y)[i] = o;
    }
}

// ---------------- epilogue: BN2 + identity + relu -> fp32 ----------------
__global__ __launch_bounds__(256)
void final_kernel(const unsigned short* __restrict__ y2, const float* __restrict__ feat,
                  const float* __restrict__ ab, float* __restrict__ out, int ntot2) {
    int i = blockIdx.x * blockDim.x + threadIdx.x;
    int stride = gridDim.x * blockDim.x;
    for (; i < ntot2; i += stride) {
        unsigned int v = ((const unsigned int*)y2)[i];
        int c0 = (i*2) & 63;
        float2 f = ((const float2*)feat)[i];
        float r0 = fmaxf(ab[c0]   * bf2f((unsigned short)(v & 0xffffu)) + ab[64 + c0]   + f.x, 0.f);
        float r1 = fmaxf(ab[c0+1] * bf2f((unsigned short)(v >> 16))     + ab[64 + c0+1] + f.y, 0.f);
        ((float2*)out)[i] = make_float2(r0, r1);
    }
}

extern "C" void kernel_launch(void* const* d_in, const int* in_sizes, int n_in,
                              void* d_out, int out_size, void* d_ws, size_t ws_size,
                              hipStream_t stream) {
    const float* features = (const float*)d_in[0];
    const int*   nbr      = (const int*)d_in[1];
    const float* valid    = (const float*)d_in[2];
    const float* W1       = (const float*)d_in[3];
    const float* gamma1   = (const float*)d_in[4];
    const float* beta1    = (const float*)d_in[5];
    const float* W2       = (const float*)d_in[6];
    const float* gamma2   = (const float*)d_in[7];
    const float* beta2    = (const float*)d_in[8];
    float* out = (float*)d_out;

    int nvox  = in_sizes[0] / 64;                 // 500000
    int nvoxp = (nvox + 255) & ~255;              // 500224 (pad to block multiple)
    size_t featB = (size_t)nvox * 64 * 2;         // 64 MB bf16 feature map

    // d_out doubles as scratch until final_kernel overwrites all of it:
    //   [0, featB)        xb (bf16 features)
    //   [featB, 2*featB)  y1 (conv1 out, bf16; BN1+ReLU applied in place)
    char* ob = (char*)d_out;
    unsigned short* xb = (unsigned short*)ob;
    unsigned short* y1 = (unsigned short*)(ob + featB);

    // d_ws (~118.6 MB):
    //   [0, 2048)      stats: sums1, sums2, ab1, ab2 (128 floats each)
    //   [2048, 2176)   zero page (128 B)
    //   [4096, ..)     Wp1, Wp2 (216 KB each)
    //   [512K, +54MB)  enc (27 * nvoxp ints)
    //   then           y2 (bf16)
    char* ws = (char*)d_ws;
    float* stats = (float*)ws;
    float* sums1 = stats;
    float* sums2 = stats + 128;
    float* ab1   = stats + 256;
    float* ab2   = stats + 384;
    const unsigned short* zrow = (const unsigned short*)(ws + 2048);
    unsigned short* Wp1 = (unsigned short*)(ws + 4096);
    unsigned short* Wp2 = (unsigned short*)(ws + 4096 + 221184);
    int* enc = (int*)(ws + 524288);
    size_t encB = (size_t)27 * nvoxp * 4;          // 54,024,192
    unsigned short* y2 = (unsigned short*)(ws + 524288 + encB);

    hipMemsetAsync(ws, 0, 4096, stream);           // stats + zero page

    convert_bf16<<<2048, 256, 0, stream>>>(features, xb, nvox * 16);
    pack_w<<<54, 256, 0, stream>>>(W1, W2, Wp1, Wp2);
    dim3 eg(nvoxp / 256, 27);
    encode_kernel<<<eg, 256, 0, stream>>>(nbr, valid, enc, nvox, nvoxp);

    int convGrid = nvoxp / 256;   // 1954
    conv_kernel<<<convGrid, 256, 0, stream>>>(xb, enc, Wp1, zrow, y1, sums1, nvox, nvoxp);
    finalize_kernel<<<1, 64, 0, stream>>>(sums1, gamma1, beta1, ab1, 1.0f / nvox);
    bnrelu_kernel<<<2048, 256, 0, stream>>>(y1, ab1, nvox * 16);
    conv_kernel<<<convGrid, 256, 0, stream>>>(y1, enc, Wp2, zrow, y2, sums2, nvox, nvoxp);
    finalize_kernel<<<1, 64, 0, stream>>>(sums2, gamma2, beta2, ab2, 1.0f / nvox);
    final_kernel<<<4096, 256, 0, stream>>>(y2, features, ab2, out, nvox * 32);
}